// Round 9
// baseline (1256.779 us; speedup 1.0000x reference)
//
#include <hip/hip_runtime.h>
#include <hip/hip_bf16.h>

#define B_ 512
#define T_ 49
#define I_ 96
#define H_ 1024

typedef __attribute__((ext_vector_type(4))) float f32x4;
typedef __attribute__((ext_vector_type(8))) short s16x8;

__device__ __forceinline__ unsigned short f2bf(float f) {
    unsigned int u = __float_as_uint(f);
    unsigned int r = (u + 0x7FFFu + ((u >> 16) & 1u)) >> 16;
    return (unsigned short)r;
}
__device__ __forceinline__ float sigmoidf_(float x) {
    return 1.0f / (1.0f + __expf(-x));
}
__device__ __forceinline__ float tanhf_(float x) {
    return 1.0f - 2.0f / (__expf(2.0f * x) + 1.0f);
}

__device__ __forceinline__ void gload_lds16(const unsigned short* g, unsigned short* l) {
    __builtin_amdgcn_global_load_lds(
        (const __attribute__((address_space(1))) void*)g,
        (__attribute__((address_space(3))) void*)l, 16, 0, 0);
}

// 2B h-store, write-through past L1/L2 to MALL (no dirty L2 lines -> no wbL2 needed)
__device__ __forceinline__ void storeHsc(unsigned short* p, unsigned short v) {
    unsigned int vv = v;
    asm volatile("global_store_short %0, %1, off sc0 sc1" :: "v"(p), "v"(vv) : "memory");
}

// ------------- quantize fp32 -> bf16; x transposed to [t][b][i];
// ------------- zeroes the sync region (every call) -------------
__global__ void quantize_kernel(const float* __restrict__ Whh,
                                const float* __restrict__ Wih,
                                const float* __restrict__ x,
                                unsigned short* __restrict__ Whh_bf,
                                unsigned short* __restrict__ Wih_bf,
                                unsigned short* __restrict__ xT_bf,
                                unsigned int* __restrict__ bar) {
    const long stride = (long)gridDim.x * blockDim.x;
    const long idx = (long)blockIdx.x * blockDim.x + threadIdx.x;

    if (blockIdx.x == 0)
        for (int i = threadIdx.x; i < T_ * 4 * 10 * 32; i += 256) bar[i] = 0;

    const long nWhh4 = (long)3 * H_ * H_ / 4;
    const long nWih4 = (long)3 * H_ * I_ / 4;
    const long nX4   = (long)B_ * T_ * I_ / 4;

    for (long i = idx; i < nWhh4; i += stride) {
        float4 v = ((const float4*)Whh)[i];
        ushort4 o; o.x = f2bf(v.x); o.y = f2bf(v.y); o.z = f2bf(v.z); o.w = f2bf(v.w);
        ((ushort4*)Whh_bf)[i] = o;
    }
    for (long i = idx; i < nWih4; i += stride) {
        float4 v = ((const float4*)Wih)[i];
        ushort4 o; o.x = f2bf(v.x); o.y = f2bf(v.y); o.z = f2bf(v.z); o.w = f2bf(v.w);
        ((ushort4*)Wih_bf)[i] = o;
    }
    for (long i = idx; i < nX4; i += stride) {
        float4 v = ((const float4*)x)[i];
        ushort4 o; o.x = f2bf(v.x); o.y = f2bf(v.y); o.z = f2bf(v.z); o.w = f2bf(v.w);
        const long e = i * 4;                 // flat elem idx in [b][t][i]
        const int b  = (int)(e / (T_ * I_));
        const int rm = (int)(e - (long)b * (T_ * I_));
        const int tt = rm / I_;
        const int ii = rm - tt * I_;
        ((ushort4*)xT_bf)[(((long)tt * B_ + b) * I_ + ii) >> 2] = o;
    }
}

// ---------------- persistent GRU (v5): write-through h + acquire-inv reads ----------------
// 256 blocks x 512 thr (8 waves = 4 mq x 2 kg), 1 block/CU, cooperative.
// h cross-block protocol (the R7/R8 hybrid):
//   writes: sc0 sc1 write-through to MALL (no dirty L2 lines anywhere)
//   arrive: pure RELAXED counting (8 subs -> root -> flag), no fences
//   poll:   RELAXED SYSTEM loads of quiet flag line (always fresh, L2-bypass)
//   read:   ONE agent-scope ACQUIRE load (emits buffer_inv; no writeback walk),
//           then NORMAL cached h loads -> per-XCD L2 dedup of the h broadcast.
// gi (x @ W_ih^T) computed BEFORE the poll: its operands are in registers
// before the inv clobbers L2. W_hh in LDS 1KB tiles (conflict-free, R7-proven).
__global__ __launch_bounds__(512)
void gru_persist5(const unsigned short* __restrict__ Whh_bf,
                  const unsigned short* __restrict__ Wih_bf,
                  const unsigned short* __restrict__ xT_bf,
                  const float* __restrict__ b_ih,
                  const float* __restrict__ b_hh,
                  unsigned short* __restrict__ hbf0,
                  unsigned short* __restrict__ hbf1,
                  float* __restrict__ out,
                  unsigned int* __restrict__ bar)
{
    __shared__ __align__(16) unsigned short Wl[96 * 512];  // 98,304 B
    __shared__ __align__(16) f32x4 Red[4 * 8 * 64];        // 32,768 B

    const int tid = threadIdx.x;
    const int w   = tid >> 6;
    const int l   = tid & 63;
    const int l15 = l & 15;
    const int l4  = l >> 4;
    const int mq  = w >> 1;      // 0..3 : 32-row slice
    const int kg  = w & 1;       // 0..1 : K half

    const int bid  = blockIdx.x;
    const int xcd  = bid & 7;
    const int r_   = bid >> 3;
    const int blkb = r_ & 3;              // 4 b-tiles of 128 (sync group)
    const int blkj = xcd * 8 + (r_ >> 2); // 64 j-tiles of 16, XCD-grouped
    const int b0   = blkb * 128;
    const int j0   = blkj * 16;
    const int jg   = j0 + l15;
    const int brow = b0 + mq * 32;
    const int sub  = blkj >> 3;           // 0..7 arrival sub-counter

    // ---- one-time: W_hh slice -> LDS tiles (async DMA; tile p = g*32+ks) ----
    for (int p = w; p < 96; p += 8) {
        const int g = p >> 5, ks = p & 31;
        const unsigned short* src = Whh_bf + ((long)g * H_ + j0 + l15) * H_ + ks * 32 + l4 * 8;
        gload_lds16(src, &Wl[p * 512]);   // dest wave-uniform; HW adds lane*16B
    }

    // ---- loop-invariant scalars/pointers ----
    const float bR   = b_ih[jg] + b_hh[jg];
    const float bZ   = b_ih[H_ + jg] + b_hh[H_ + jg];
    const float bihN = b_ih[2 * H_ + jg];
    const float bhhN = b_hh[2 * H_ + jg];

    const unsigned short* Vr = Wih_bf + (long)(j0 + l15) * I_ + l4 * 8;
    const unsigned short* Vz = Vr + (long)H_ * I_;
    const unsigned short* Vn = Vz + (long)H_ * I_;

    float hreg[2][4] = {{0.f,0.f,0.f,0.f},{0.f,0.f,0.f,0.f}};  // kg0 h state

    __syncthreads();   // drains W DMA (vmcnt 0 at barrier)

    for (int t = 0; t < T_; ++t) {
        const unsigned short* hin  = (t & 1) ? hbf1 : hbf0;
        unsigned short*       hout = (t & 1) ? hbf0 : hbf1;
        unsigned int* barT = bar + ((t * 4 + blkb) * 10) * 32;

        f32x4 accR[2], accZ[2], accNh[2], accNi[2];
#pragma unroll
        for (int m = 0; m < 2; ++m) {
            accR[m]  = (f32x4){0.f, 0.f, 0.f, 0.f};
            accZ[m]  = (f32x4){0.f, 0.f, 0.f, 0.f};
            accNh[m] = (f32x4){0.f, 0.f, 0.f, 0.f};
            accNi[m] = (f32x4){0.f, 0.f, 0.f, 0.f};
        }

        // ---- kg1: input GEMM gi = x_t @ W_ih^T (issued BEFORE poll/inv) ----
        if (kg == 1) {
            const unsigned short* Ax0 = xT_bf + ((long)t * B_ + brow + l15) * I_ + l4 * 8;
            const unsigned short* Ax1 = Ax0 + 16 * I_;
#pragma unroll
            for (int ks = 0; ks < 3; ++ks) {
                s16x8 a0 = *(const s16x8*)(Ax0 + ks * 32);
                s16x8 a1 = *(const s16x8*)(Ax1 + ks * 32);
                s16x8 br = *(const s16x8*)(Vr + ks * 32);
                s16x8 bz = *(const s16x8*)(Vz + ks * 32);
                s16x8 bn = *(const s16x8*)(Vn + ks * 32);
                accR[0]  = __builtin_amdgcn_mfma_f32_16x16x32_bf16(a0, br, accR[0], 0, 0, 0);
                accR[1]  = __builtin_amdgcn_mfma_f32_16x16x32_bf16(a1, br, accR[1], 0, 0, 0);
                accZ[0]  = __builtin_amdgcn_mfma_f32_16x16x32_bf16(a0, bz, accZ[0], 0, 0, 0);
                accZ[1]  = __builtin_amdgcn_mfma_f32_16x16x32_bf16(a1, bz, accZ[1], 0, 0, 0);
                accNi[0] = __builtin_amdgcn_mfma_f32_16x16x32_bf16(a0, bn, accNi[0], 0, 0, 0);
                accNi[1] = __builtin_amdgcn_mfma_f32_16x16x32_bf16(a1, bn, accNi[1], 0, 0, 0);
            }
        }

        if (t > 0) {
            // ---- poll previous step's group flag (quiet line, bypass loads) ----
            const unsigned int* flag_tm1 = bar + (((t - 1) * 4 + blkb) * 10 + 9) * 32;
            while (__hip_atomic_load(flag_tm1, __ATOMIC_RELAXED,
                                     __HIP_MEMORY_SCOPE_SYSTEM) == 0)
                __builtin_amdgcn_s_sleep(1);
            // ONE agent acquire: L1/L2 invalidate (no writeback walk). h loads
            // below then refetch fresh from MALL and re-dedup in this XCD's L2.
            (void)__hip_atomic_load(flag_tm1, __ATOMIC_ACQUIRE,
                                    __HIP_MEMORY_SCOPE_AGENT);

            // ---- recurrent GEMM: K-half kg; W from LDS, A ring-6 cached ----
            const unsigned short* Ab0 = hin + (long)(brow + l15) * H_ + kg * 512 + l4 * 8;
            const unsigned short* Ab1 = Ab0 + 16 * H_;

            s16x8 ar[6][2];
#pragma unroll
            for (int p = 0; p < 6; ++p) {
                ar[p][0] = *(const s16x8*)(Ab0 + p * 32);
                ar[p][1] = *(const s16x8*)(Ab1 + p * 32);
            }
#pragma unroll
            for (int s = 0; s < 16; ++s) {
                const int slot = s % 6;
                s16x8 a0 = ar[slot][0];
                s16x8 a1 = ar[slot][1];
                if (s < 10) {
                    ar[slot][0] = *(const s16x8*)(Ab0 + (s + 6) * 32);
                    ar[slot][1] = *(const s16x8*)(Ab1 + (s + 6) * 32);
                }
                const int ksg = kg * 16 + s;
                const unsigned short* wt = &Wl[ksg * 512 + l * 8];
                s16x8 br = *(const s16x8*)(wt);
                s16x8 bz = *(const s16x8*)(wt + 32 * 512);
                s16x8 bn = *(const s16x8*)(wt + 64 * 512);
                accR[0]  = __builtin_amdgcn_mfma_f32_16x16x32_bf16(a0, br, accR[0], 0, 0, 0);
                accR[1]  = __builtin_amdgcn_mfma_f32_16x16x32_bf16(a1, br, accR[1], 0, 0, 0);
                accZ[0]  = __builtin_amdgcn_mfma_f32_16x16x32_bf16(a0, bz, accZ[0], 0, 0, 0);
                accZ[1]  = __builtin_amdgcn_mfma_f32_16x16x32_bf16(a1, bz, accZ[1], 0, 0, 0);
                accNh[0] = __builtin_amdgcn_mfma_f32_16x16x32_bf16(a0, bn, accNh[0], 0, 0, 0);
                accNh[1] = __builtin_amdgcn_mfma_f32_16x16x32_bf16(a1, bn, accNh[1], 0, 0, 0);
            }
        }

        // ---- merge kg partials via LDS ----
        __syncthreads();
        if (kg == 1) {
            f32x4* dst = &Red[(mq * 8) * 64 + l];
            dst[0 * 64] = accR[0];  dst[1 * 64] = accR[1];
            dst[2 * 64] = accZ[0];  dst[3 * 64] = accZ[1];
            dst[4 * 64] = accNh[0]; dst[5 * 64] = accNh[1];
            dst[6 * 64] = accNi[0]; dst[7 * 64] = accNi[1];
        }
        __syncthreads();

        if (kg == 0) {
            const f32x4* srcp = &Red[(mq * 8) * 64 + l];
            accR[0]  += srcp[0 * 64]; accR[1]  += srcp[1 * 64];
            accZ[0]  += srcp[2 * 64]; accZ[1]  += srcp[3 * 64];
            accNh[0] += srcp[4 * 64]; accNh[1] += srcp[5 * 64];
            accNi[0] += srcp[6 * 64]; accNi[1] += srcp[7 * 64];

#pragma unroll
            for (int f = 0; f < 2; ++f) {
#pragma unroll
                for (int r = 0; r < 4; ++r) {
                    const float rg = sigmoidf_(accR[f][r] + bR);
                    const float zg = sigmoidf_(accZ[f][r] + bZ);
                    const float ng = tanhf_(accNi[f][r] + bihN + rg * (accNh[f][r] + bhhN));
                    hreg[f][r] = (1.0f - zg) * ng + zg * hreg[f][r];
                    const long off = (long)(brow + f * 16 + l4 * 4 + r) * H_ + jg;
                    if (t < T_ - 1) storeHsc(hout + off, f2bf(hreg[f][r]));
                    else            out[off] = hreg[f][r];
                }
            }
        }

        // ---- arrive: pure relaxed counting (write-through stores already at MALL) ----
        if (t < T_ - 1) {
            __syncthreads();   // all waves' sc h-stores acked
            if (tid == 0) {
                unsigned int* scnt = barT + sub * 32;
                unsigned int* root = barT + 8 * 32;
                unsigned int* flag = barT + 9 * 32;
                unsigned int old = __hip_atomic_fetch_add(scnt, 1u, __ATOMIC_RELAXED,
                                                          __HIP_MEMORY_SCOPE_SYSTEM);
                if (old == 7) {
                    unsigned int o2 = __hip_atomic_fetch_add(root, 1u, __ATOMIC_RELAXED,
                                                             __HIP_MEMORY_SCOPE_SYSTEM);
                    if (o2 == 7)
                        __hip_atomic_store(flag, 1u, __ATOMIC_RELAXED,
                                           __HIP_MEMORY_SCOPE_SYSTEM);
                }
            }
        }
    }
}

extern "C" void kernel_launch(void* const* d_in, const int* in_sizes, int n_in,
                              void* d_out, int out_size, void* d_ws, size_t ws_size,
                              hipStream_t stream) {
    const float* enc_in = (const float*)d_in[0];
    const float* W_ih   = (const float*)d_in[1];
    const float* W_hh   = (const float*)d_in[2];
    const float* b_ih   = (const float*)d_in[3];
    const float* b_hh   = (const float*)d_in[4];
    float* out = (float*)d_out;

    char* ws = (char*)d_ws;
    unsigned short* Whh_bf = (unsigned short*)(ws);             // 6,291,456 B
    unsigned short* Wih_bf = (unsigned short*)(ws + 6291456);   //   589,824 B
    unsigned short* xT_bf  = (unsigned short*)(ws + 6881280);   // 4,816,896 B
    unsigned short* hbf0   = (unsigned short*)(ws + 11698176);  // 1,048,576 B
    unsigned short* hbf1   = (unsigned short*)(ws + 12746752);  // 1,048,576 B
    unsigned int*   bar    = (unsigned int*)(ws + 13795328);    //   250,880 B

    quantize_kernel<<<dim3(1024), dim3(256), 0, stream>>>(W_hh, W_ih, enc_in,
                                                          Whh_bf, Wih_bf, xT_bf, bar);

    void* args[] = {(void*)&Whh_bf, (void*)&Wih_bf, (void*)&xT_bf,
                    (void*)&b_ih, (void*)&b_hh,
                    (void*)&hbf0, (void*)&hbf1, (void*)&out, (void*)&bar};
    hipLaunchCooperativeKernel((const void*)gru_persist5,
                               dim3(256), dim3(512), args, 0, stream);
}

// Round 10
// 917.726 us; speedup vs baseline: 1.3694x; 1.3694x over previous
//
#include <hip/hip_runtime.h>
#include <hip/hip_bf16.h>

#define B_ 512
#define T_ 49
#define I_ 96
#define H_ 1024

typedef __attribute__((ext_vector_type(4))) float f32x4;
typedef __attribute__((ext_vector_type(8))) short s16x8;

__device__ __forceinline__ unsigned short f2bf(float f) {
    unsigned int u = __float_as_uint(f);
    unsigned int r = (u + 0x7FFFu + ((u >> 16) & 1u)) >> 16;
    return (unsigned short)r;
}
__device__ __forceinline__ float sigmoidf_(float x) {
    return 1.0f / (1.0f + __expf(-x));
}
__device__ __forceinline__ float tanhf_(float x) {
    return 1.0f - 2.0f / (__expf(2.0f * x) + 1.0f);
}

__device__ __forceinline__ void gload_lds16(const unsigned short* g, unsigned short* l) {
    __builtin_amdgcn_global_load_lds(
        (const __attribute__((address_space(1))) void*)g,
        (__attribute__((address_space(3))) void*)l, 16, 0, 0);
}

// 16B h-load, L1/L2-bypass: two relaxed system-scope 8B atomic loads (R8-proven)
__device__ __forceinline__ s16x8 loadA16sc(const unsigned short* p) {
    union { unsigned long long q[2]; s16x8 v; } u;
    u.q[0] = __hip_atomic_load((const unsigned long long*)p,
                               __ATOMIC_RELAXED, __HIP_MEMORY_SCOPE_SYSTEM);
    u.q[1] = __hip_atomic_load((const unsigned long long*)(p + 4),
                               __ATOMIC_RELAXED, __HIP_MEMORY_SCOPE_SYSTEM);
    return u.v;
}

// 2B h-store, write-through past L1/L2 to MALL (no dirty L2 lines anywhere)
__device__ __forceinline__ void storeHsc(unsigned short* p, unsigned short v) {
    unsigned int vv = v;
    asm volatile("global_store_short %0, %1, off sc0 sc1" :: "v"(p), "v"(vv) : "memory");
}

// ------------- quantize fp32 -> bf16; x transposed to [t][b][i];
// ------------- zeroes the flag region (every call) -------------
__global__ void quantize_kernel(const float* __restrict__ Whh,
                                const float* __restrict__ Wih,
                                const float* __restrict__ x,
                                unsigned short* __restrict__ Whh_bf,
                                unsigned short* __restrict__ Wih_bf,
                                unsigned short* __restrict__ xT_bf,
                                unsigned int* __restrict__ bar) {
    const long stride = (long)gridDim.x * blockDim.x;
    const long idx = (long)blockIdx.x * blockDim.x + threadIdx.x;

    if (blockIdx.x == 0)
        for (int i = threadIdx.x; i < T_ * 4 * 64; i += 256) bar[i] = 0;

    const long nWhh4 = (long)3 * H_ * H_ / 4;
    const long nWih4 = (long)3 * H_ * I_ / 4;
    const long nX4   = (long)B_ * T_ * I_ / 4;

    for (long i = idx; i < nWhh4; i += stride) {
        float4 v = ((const float4*)Whh)[i];
        ushort4 o; o.x = f2bf(v.x); o.y = f2bf(v.y); o.z = f2bf(v.z); o.w = f2bf(v.w);
        ((ushort4*)Whh_bf)[i] = o;
    }
    for (long i = idx; i < nWih4; i += stride) {
        float4 v = ((const float4*)Wih)[i];
        ushort4 o; o.x = f2bf(v.x); o.y = f2bf(v.y); o.z = f2bf(v.z); o.w = f2bf(v.w);
        ((ushort4*)Wih_bf)[i] = o;
    }
    for (long i = idx; i < nX4; i += stride) {
        float4 v = ((const float4*)x)[i];
        ushort4 o; o.x = f2bf(v.x); o.y = f2bf(v.y); o.z = f2bf(v.z); o.w = f2bf(v.w);
        const long e = i * 4;                 // flat elem idx in [b][t][i]
        const int b  = (int)(e / (T_ * I_));
        const int rm = (int)(e - (long)b * (T_ * I_));
        const int tt = rm / I_;
        const int ii = rm - tt * I_;
        ((ushort4*)xT_bf)[(((long)tt * B_ + b) * I_ + ii) >> 2] = o;
    }
}

// ---------------- persistent GRU (v6): flag-array sync, fence-free ----------------
// 256 blocks x 512 thr (8 waves = 4 mq x 2 kg), 1 block/CU, cooperative.
// Data path (R8-proven): h stores sc0 sc1 write-through to MALL; h loads are
// system-scope relaxed bypass loads. NO fences at all -> x/W_ih/bias stay
// L2-resident across all 49 steps.
// Sync (new): per (t, blkb-group) a 64-dword flag array. Producer block stores
// 1 to flags[blkj] (plain parallel store, no RMW chain). Consumers poll all 64
// flags with ONE 64-lane vector bypass load + __all ballot. O(1) depth.
__global__ __launch_bounds__(512)
void gru_persist6(const unsigned short* __restrict__ Whh_bf,
                  const unsigned short* __restrict__ Wih_bf,
                  const unsigned short* __restrict__ xT_bf,
                  const float* __restrict__ b_ih,
                  const float* __restrict__ b_hh,
                  unsigned short* __restrict__ hbf0,
                  unsigned short* __restrict__ hbf1,
                  float* __restrict__ out,
                  unsigned int* __restrict__ bar)
{
    __shared__ __align__(16) unsigned short Wl[96 * 512];  // 98,304 B
    __shared__ __align__(16) f32x4 Red[4 * 8 * 64];        // 32,768 B

    const int tid = threadIdx.x;
    const int w   = tid >> 6;
    const int l   = tid & 63;
    const int l15 = l & 15;
    const int l4  = l >> 4;
    const int mq  = w >> 1;      // 0..3 : 32-row slice
    const int kg  = w & 1;       // 0..1 : K half

    const int bid  = blockIdx.x;
    const int xcd  = bid & 7;
    const int r_   = bid >> 3;
    const int blkb = r_ & 3;              // 4 b-tiles of 128 (sync group)
    const int blkj = xcd * 8 + (r_ >> 2); // 64 j-tiles of 16, XCD-grouped
    const int b0   = blkb * 128;
    const int j0   = blkj * 16;
    const int jg   = j0 + l15;
    const int brow = b0 + mq * 32;

    // ---- one-time: W_hh slice -> LDS tiles (async DMA; tile p = g*32+ks) ----
    for (int p = w; p < 96; p += 8) {
        const int g = p >> 5, ks = p & 31;
        const unsigned short* src = Whh_bf + ((long)g * H_ + j0 + l15) * H_ + ks * 32 + l4 * 8;
        gload_lds16(src, &Wl[p * 512]);   // dest wave-uniform; HW adds lane*16B
    }

    // ---- loop-invariant scalars/pointers (plain cached, stay L2-warm) ----
    const float bR   = b_ih[jg] + b_hh[jg];
    const float bZ   = b_ih[H_ + jg] + b_hh[H_ + jg];
    const float bihN = b_ih[2 * H_ + jg];
    const float bhhN = b_hh[2 * H_ + jg];

    const unsigned short* Vr = Wih_bf + (long)(j0 + l15) * I_ + l4 * 8;
    const unsigned short* Vz = Vr + (long)H_ * I_;
    const unsigned short* Vn = Vz + (long)H_ * I_;

    float hreg[2][4] = {{0.f,0.f,0.f,0.f},{0.f,0.f,0.f,0.f}};  // kg0 h state

    __syncthreads();   // drains W DMA (vmcnt 0 at barrier)

    for (int t = 0; t < T_; ++t) {
        const unsigned short* hin  = (t & 1) ? hbf1 : hbf0;
        unsigned short*       hout = (t & 1) ? hbf0 : hbf1;

        f32x4 accR[2], accZ[2], accNh[2], accNi[2];
#pragma unroll
        for (int m = 0; m < 2; ++m) {
            accR[m]  = (f32x4){0.f, 0.f, 0.f, 0.f};
            accZ[m]  = (f32x4){0.f, 0.f, 0.f, 0.f};
            accNh[m] = (f32x4){0.f, 0.f, 0.f, 0.f};
            accNi[m] = (f32x4){0.f, 0.f, 0.f, 0.f};
        }

        // ---- kg1: input GEMM gi = x_t @ W_ih^T (h-independent, pre-poll) ----
        if (kg == 1) {
            const unsigned short* Ax0 = xT_bf + ((long)t * B_ + brow + l15) * I_ + l4 * 8;
            const unsigned short* Ax1 = Ax0 + 16 * I_;
#pragma unroll
            for (int ks = 0; ks < 3; ++ks) {
                s16x8 a0 = *(const s16x8*)(Ax0 + ks * 32);
                s16x8 a1 = *(const s16x8*)(Ax1 + ks * 32);
                s16x8 br = *(const s16x8*)(Vr + ks * 32);
                s16x8 bz = *(const s16x8*)(Vz + ks * 32);
                s16x8 bn = *(const s16x8*)(Vn + ks * 32);
                accR[0]  = __builtin_amdgcn_mfma_f32_16x16x32_bf16(a0, br, accR[0], 0, 0, 0);
                accR[1]  = __builtin_amdgcn_mfma_f32_16x16x32_bf16(a1, br, accR[1], 0, 0, 0);
                accZ[0]  = __builtin_amdgcn_mfma_f32_16x16x32_bf16(a0, bz, accZ[0], 0, 0, 0);
                accZ[1]  = __builtin_amdgcn_mfma_f32_16x16x32_bf16(a1, bz, accZ[1], 0, 0, 0);
                accNi[0] = __builtin_amdgcn_mfma_f32_16x16x32_bf16(a0, bn, accNi[0], 0, 0, 0);
                accNi[1] = __builtin_amdgcn_mfma_f32_16x16x32_bf16(a1, bn, accNi[1], 0, 0, 0);
            }
        }

        if (t > 0) {
            // ---- poll: one 64-lane sweep of the 64 group flags (bypass loads) ----
            const unsigned int* fl = bar + ((long)(t - 1) * 4 + blkb) * 64 + l;
            for (;;) {
                unsigned int f = __hip_atomic_load(fl, __ATOMIC_RELAXED,
                                                   __HIP_MEMORY_SCOPE_SYSTEM);
                if (__all(f != 0)) break;
                __builtin_amdgcn_s_sleep(1);
            }
            asm volatile("" ::: "memory");

            // ---- recurrent GEMM: K-half kg; W from LDS, A ring-8x2 bypass ----
            const unsigned short* Ab0 = hin + (long)(brow + l15) * H_ + kg * 512 + l4 * 8;
            const unsigned short* Ab1 = Ab0 + 16 * H_;

            s16x8 ar[8][2];
#pragma unroll
            for (int p = 0; p < 8; ++p) {
                ar[p][0] = loadA16sc(Ab0 + p * 32);
                ar[p][1] = loadA16sc(Ab1 + p * 32);
            }
#pragma unroll
            for (int s = 0; s < 16; ++s) {
                const int slot = s & 7;
                s16x8 a0 = ar[slot][0];
                s16x8 a1 = ar[slot][1];
                if (s < 8) {
                    ar[slot][0] = loadA16sc(Ab0 + (s + 8) * 32);
                    ar[slot][1] = loadA16sc(Ab1 + (s + 8) * 32);
                }
                const int ksg = kg * 16 + s;
                const unsigned short* wt = &Wl[ksg * 512 + l * 8];
                s16x8 br = *(const s16x8*)(wt);
                s16x8 bz = *(const s16x8*)(wt + 32 * 512);
                s16x8 bn = *(const s16x8*)(wt + 64 * 512);
                accR[0]  = __builtin_amdgcn_mfma_f32_16x16x32_bf16(a0, br, accR[0], 0, 0, 0);
                accR[1]  = __builtin_amdgcn_mfma_f32_16x16x32_bf16(a1, br, accR[1], 0, 0, 0);
                accZ[0]  = __builtin_amdgcn_mfma_f32_16x16x32_bf16(a0, bz, accZ[0], 0, 0, 0);
                accZ[1]  = __builtin_amdgcn_mfma_f32_16x16x32_bf16(a1, bz, accZ[1], 0, 0, 0);
                accNh[0] = __builtin_amdgcn_mfma_f32_16x16x32_bf16(a0, bn, accNh[0], 0, 0, 0);
                accNh[1] = __builtin_amdgcn_mfma_f32_16x16x32_bf16(a1, bn, accNh[1], 0, 0, 0);
            }
        }

        // ---- merge kg partials via LDS ----
        __syncthreads();
        if (kg == 1) {
            f32x4* dst = &Red[(mq * 8) * 64 + l];
            dst[0 * 64] = accR[0];  dst[1 * 64] = accR[1];
            dst[2 * 64] = accZ[0];  dst[3 * 64] = accZ[1];
            dst[4 * 64] = accNh[0]; dst[5 * 64] = accNh[1];
            dst[6 * 64] = accNi[0]; dst[7 * 64] = accNi[1];
        }
        __syncthreads();

        if (kg == 0) {
            const f32x4* srcp = &Red[(mq * 8) * 64 + l];
            accR[0]  += srcp[0 * 64]; accR[1]  += srcp[1 * 64];
            accZ[0]  += srcp[2 * 64]; accZ[1]  += srcp[3 * 64];
            accNh[0] += srcp[4 * 64]; accNh[1] += srcp[5 * 64];
            accNi[0] += srcp[6 * 64]; accNi[1] += srcp[7 * 64];

#pragma unroll
            for (int f = 0; f < 2; ++f) {
#pragma unroll
                for (int r = 0; r < 4; ++r) {
                    const float rg = sigmoidf_(accR[f][r] + bR);
                    const float zg = sigmoidf_(accZ[f][r] + bZ);
                    const float ng = tanhf_(accNi[f][r] + bihN + rg * (accNh[f][r] + bhhN));
                    hreg[f][r] = (1.0f - zg) * ng + zg * hreg[f][r];
                    const long off = (long)(brow + f * 16 + l4 * 4 + r) * H_ + jg;
                    if (t < T_ - 1) storeHsc(hout + off, f2bf(hreg[f][r]));
                    else            out[off] = hreg[f][r];
                }
            }
        }

        // ---- arrive: ONE parallel flag store per block (no RMW chain) ----
        if (t < T_ - 1) {
            __syncthreads();   // all waves' sc h-stores acked at MALL
            if (tid == 0)
                __hip_atomic_store(bar + ((long)t * 4 + blkb) * 64 + blkj, 1u,
                                   __ATOMIC_RELAXED, __HIP_MEMORY_SCOPE_SYSTEM);
        }
    }
}

extern "C" void kernel_launch(void* const* d_in, const int* in_sizes, int n_in,
                              void* d_out, int out_size, void* d_ws, size_t ws_size,
                              hipStream_t stream) {
    const float* enc_in = (const float*)d_in[0];
    const float* W_ih   = (const float*)d_in[1];
    const float* W_hh   = (const float*)d_in[2];
    const float* b_ih   = (const float*)d_in[3];
    const float* b_hh   = (const float*)d_in[4];
    float* out = (float*)d_out;

    char* ws = (char*)d_ws;
    unsigned short* Whh_bf = (unsigned short*)(ws);             // 6,291,456 B
    unsigned short* Wih_bf = (unsigned short*)(ws + 6291456);   //   589,824 B
    unsigned short* xT_bf  = (unsigned short*)(ws + 6881280);   // 4,816,896 B
    unsigned short* hbf0   = (unsigned short*)(ws + 11698176);  // 1,048,576 B
    unsigned short* hbf1   = (unsigned short*)(ws + 12746752);  // 1,048,576 B
    unsigned int*   bar    = (unsigned int*)(ws + 13795328);    //    50,176 B

    quantize_kernel<<<dim3(1024), dim3(256), 0, stream>>>(W_hh, W_ih, enc_in,
                                                          Whh_bf, Wih_bf, xT_bf, bar);

    void* args[] = {(void*)&Whh_bf, (void*)&Wih_bf, (void*)&xT_bf,
                    (void*)&b_ih, (void*)&b_hh,
                    (void*)&hbf0, (void*)&hbf1, (void*)&out, (void*)&bar};
    hipLaunchCooperativeKernel((const void*)gru_persist6,
                               dim3(256), dim3(512), args, 0, stream);
}